// Round 7
// baseline (117.270 us; speedup 1.0000x reference)
//
#include <hip/hip_runtime.h>

#define BATCH 131072
#define IN 128
#define OUT 128
#define PNUM 16
#define WPITCH 136   // f16 pitch, w tile: 272B rows, frag reads land conflict-free
#define XPITCH 136   // f16 pitch, x bounce: same geometry as w tile
#define OPITCH 132   // f32 pitch, out bounce: 528B rows -> slot (33m+4nt+q)%8, 2-way max
#define NITER 4
#define ROWS_PER_BLOCK (64 * NITER)   // 4 waves x 16 rows x 4 pipelined tiles

typedef _Float16 f16x8 __attribute__((ext_vector_type(8)));
typedef _Float16 f16x4 __attribute__((ext_vector_type(4)));
typedef float f32x4 __attribute__((ext_vector_type(4)));

// w[o*IN + i] = (f16) sum_p coef[o][i][p]
__global__ __launch_bounds__(256) void prep_w_kernel(const float* __restrict__ coef,
                                                     _Float16* __restrict__ w) {
    int t = blockIdx.x * blockDim.x + threadIdx.x;
    const float4* p = (const float4*)(coef + (size_t)t * PNUM);
    float4 a = p[0], b = p[1], c = p[2], d = p[3];
    float s = (a.x + a.y + a.z + a.w) + (b.x + b.y + b.z + b.w)
            + (c.x + c.y + c.z + c.w) + (d.x + d.y + d.z + d.w);
    w[t] = (_Float16)s;
}

// Round-6 structure (wave-contiguous VMEM + LDS bounce: gemm ~43 -> ~30us)
// + 4-tile pipelined loop: grid 512 (whole grid co-resident, ONE ramp instead
// of 8 block generations), w staged once per block (not 8x), and register-
// double-buffered x so tile t+1's 8 contiguous 1KB loads are in flight under
// tile t's tanh/MFMA/bounce/store (~1000+ cy of cover per iteration).
// All global instructions remain wave-contiguous: 64 lanes x 16B = two full
// rows per instruction. Intra-wave ds_write->ds_read needs no barriers.
__global__ __launch_bounds__(256, 2) void gemm_tanh_kernel(const float* __restrict__ x,
                                                           const _Float16* __restrict__ w,
                                                           const float* __restrict__ trange,
                                                           float* __restrict__ out) {
    __shared__ _Float16 wlds[OUT * WPITCH];                      // 34816 B
    __shared__ __align__(16) unsigned char scratch[4][16 * OPITCH * 4]; // 4 x 8448 B

    // tanh(v) = 1 - 2/(exp2(v * 2*log2e) + 1); fold t and 2*log2e into one scale
    const float ts = trange[0] * 2.8853900817779268f;
    const int tid  = threadIdx.x;
    const int lane = tid & 63;
    const int wv   = tid >> 6;        // 0..3
    const int m    = lane & 15;
    const int q    = lane >> 4;       // 0..3
    const int s    = lane & 31;       // 0..31
    const int half = lane >> 5;       // 0..1

    // 1. w stage FIRST (in-order vmcnt: the barrier's ds_write wait drains only
    //    w loads, not the x loads issued below). 64 f16 per thread.
#pragma unroll
    for (int i = 0; i < 8; ++i) {
        int idx = (i * 256 + tid) * 8;          // f16 index, 8 per thread per pass
        int r = idx >> 7;
        int c = idx & 127;
        *(f16x8*)&wlds[r * WPITCH + c] = *(const f16x8*)(w + idx);
    }

    // wave's row block for tile it: wrow0 + it*64 + (2j+half)
    const int wrow0 = blockIdx.x * ROWS_PER_BLOCK + wv * 16;

    // 2. prologue: tile-0 loads, wave-contiguous (instr j = rows 2j,2j+1 whole)
    f32x4 xv[2][8];
#pragma unroll
    for (int j = 0; j < 8; ++j) {
        xv[0][j] = *reinterpret_cast<const f32x4*>(
            x + (size_t)(wrow0 + 2 * j + half) * IN + s * 4);
    }
    __builtin_amdgcn_sched_barrier(0);   // pin the batch (round-4 lesson: the
    __syncthreads();                     // scheduler otherwise sinks loads)

    _Float16* xb = (_Float16*)scratch[wv];   // 16 rows x XPITCH f16 (4352 B used)
    float*    ob = (float*)scratch[wv];      // 16 rows x OPITCH f32 (aliases xb;
                                             // sequential lifetimes, same wave)

#pragma unroll
    for (int it = 0; it < NITER; ++it) {
        const int cur = it & 1;              // compile-time after full unroll

        // 2a. prefetch tile it+1 into the other register buffer; pinned here so
        //     all 8 stay outstanding across this tile's compute+store.
        if (it + 1 < NITER) {
#pragma unroll
            for (int j = 0; j < 8; ++j) {
                xv[cur ^ 1][j] = *reinterpret_cast<const f32x4*>(
                    x + (size_t)(wrow0 + (it + 1) * 64 + 2 * j + half) * IN + s * 4);
            }
        }
        __builtin_amdgcn_sched_barrier(0);

        // 3. tanh -> f16, bounce into xb (waits only on this tile's loads;
        //    prefetch stays in flight at vmcnt(8))
#pragma unroll
        for (int j = 0; j < 8; ++j) {
            f32x4 a = xv[cur][j];
            f16x4 h;
#pragma unroll
            for (int e = 0; e < 4; ++e) {
                float ea = __builtin_amdgcn_exp2f(a[e] * ts);
                h[e] = (_Float16)__builtin_fmaf(-2.0f, __builtin_amdgcn_rcpf(ea + 1.0f), 1.0f);
            }
            *(f16x4*)&xb[(2 * j + half) * XPITCH + s * 4] = h;
        }

        // 4. A fragments via ds_read_b128 (values identical to rounds 0-5)
        f16x8 af[4];
#pragma unroll
        for (int ks = 0; ks < 4; ++ks) {
            af[ks] = *(const f16x8*)&xb[m * XPITCH + ks * 32 + q * 8];
        }

        // 5. MFMA over all 8 col-tiles; A = w (from LDS), B = tanh(x) fragment
        f32x4 acc[8];
#pragma unroll
        for (int nt = 0; nt < 8; ++nt) acc[nt] = (f32x4){0.f, 0.f, 0.f, 0.f};

#pragma unroll
        for (int ks = 0; ks < 4; ++ks) {
            const int kb = ks * 32 + q * 8;
#pragma unroll
            for (int nt = 0; nt < 8; ++nt) {
                f16x8 bf = *(const f16x8*)&wlds[(nt * 16 + m) * WPITCH + kb];
                acc[nt] = __builtin_amdgcn_mfma_f32_16x16x32_f16(bf, af[ks], acc[nt], 0, 0, 0);
            }
        }

        // 6. bounce acc into ob: lane (m,q) owns out[row m][nt*16+q*4 ..+3]
        //    (af[] already in registers; safe to overwrite the aliased region)
#pragma unroll
        for (int nt = 0; nt < 8; ++nt) {
            *(f32x4*)&ob[m * OPITCH + nt * 16 + q * 4] = acc[nt];
        }

        // 7. linear read-back + wave-contiguous stores (instr j = rows 2j,2j+1)
#pragma unroll
        for (int j = 0; j < 8; ++j) {
            f32x4 o = *(const f32x4*)&ob[(2 * j + half) * OPITCH + s * 4];
            *reinterpret_cast<f32x4*>(
                out + (size_t)(wrow0 + it * 64 + 2 * j + half) * OUT + s * 4) = o;
        }
    }
}

extern "C" void kernel_launch(void* const* d_in, const int* in_sizes, int n_in,
                              void* d_out, int out_size, void* d_ws, size_t ws_size,
                              hipStream_t stream) {
    const float* x    = (const float*)d_in[0];
    const float* coef = (const float*)d_in[1];
    const float* tr   = (const float*)d_in[2];
    float* out = (float*)d_out;
    _Float16* w = (_Float16*)d_ws;   // 32 KB scratch

    prep_w_kernel<<<(OUT * IN) / 256, 256, 0, stream>>>(coef, w);
    gemm_tanh_kernel<<<BATCH / ROWS_PER_BLOCK, 256, 0, stream>>>(x, w, tr, out);
}